// Round 17
// baseline (418.897 us; speedup 1.0000x reference)
//
#include <hip/hip_runtime.h>
#include <hip/hip_bf16.h>
#include <cstdint>

#define DI __device__ __forceinline__

using bf16x8 = __attribute__((ext_vector_type(8))) short;
using f32x4  = __attribute__((ext_vector_type(4))) float;

constexpr int IN_DIM = 384;
constexpr int HID    = 512;
constexpr int KTOT   = IN_DIM * 20;          // 7680: k = i*20 + t
constexpr int BM = 128, BN = 128, BK = 160;  // 8 input dims per K-step
constexpr int NSTEP = KTOT / BK;             // 48
// FULL double-buffer (A and B), ONE barrier per step: stage(s+1) overlaps compute(s).
// A: stride 320 + bijective XOR swizzle (addr ^ (row&7)<<4) on write & read -- R9-verbatim.
// B: row-major 320B, /20 monotone chunk map, DMA chunk-linear dest -- R13-verbatim.
//    (B-relayout direction parked: 3 variants failed identically; R13's B reads are
//     already floor-achieving per bank arithmetic.)
constexpr int A_STRIDE_B = 320;
constexpr int B_STRIDE_B = 320;
constexpr int A_BYTES    = BM * A_STRIDE_B;        // 40960
constexpr int B_BYTES    = BN * B_STRIDE_B;        // 40960
constexpr int LDS_BYTES  = 2 * A_BYTES + 2 * B_BYTES;  // 163840 = 160 KiB exactly

DI unsigned short f2bf(float f) {
  union { float f; uint32_t u; } v; v.f = f;
  uint32_t r = (v.u + 0x7FFFu + ((v.u >> 16) & 1u)) >> 16;
  return (unsigned short)r;
}
DI float fast_tanh(float x) {
  float e = __expf(2.0f * x);
  return 1.0f - 2.0f / (e + 1.0f);
}
DI uint32_t swzw(uint32_t L) { return L ^ ((L >> 6) & 0x70u); }

#define GLOAD_LDS16(g, l)                                                        \
  __builtin_amdgcn_global_load_lds((const __attribute__((address_space(1))) void*)(g), \
                                   (__attribute__((address_space(3))) void*)(l), 16, 0, 0)

// ---------------- pack base_weight + spline_weight -> bf16 W[o][k], k = i*20 + t ----------------
__global__ __launch_bounds__(256) void kpack(const float* __restrict__ bw,
                                             const float* __restrict__ sw,
                                             unsigned short* __restrict__ Wb) {
  int idx = blockIdx.x * 256 + threadIdx.x;
  const float* s = sw + (size_t)idx * 19;
  unsigned short* d = Wb + (size_t)idx * 20;
  d[0] = f2bf(bw[idx]);
#pragma unroll
  for (int c = 0; c < 19; ++c) d[1 + c] = f2bf(s[c]);
}

// ---------------- fused KAN GEMM: h = tanh(A(x) @ W^T) ----------------
// 8 waves, wave grid 2(M) x 4(N), wave tile 64x32, acc[4][2]. One barrier per K-step.
__global__ __launch_bounds__(512, 2) void kgemm1(const float* __restrict__ z,
                                                 const float* __restrict__ ms,
                                                 const float* __restrict__ md,
                                                 const unsigned short* __restrict__ Wb,
                                                 unsigned short* __restrict__ hout) {
  extern __shared__ char ldsbuf[];
  // layout: [A0 @0][A1 @40960][B0 @81920][B1 @122880]; scalar offset selects (no ptr arrays)

  const int tid  = threadIdx.x;
  const int lane = tid & 63;
  const int wv   = tid >> 6;                  // 0..7
  const int wr   = wv >> 2;                   // 0..1 : M strip (64 rows)
  const int wc   = wv & 3;                    // 0..3 : N strip (32 cols)
  const int l16  = lane & 15;
  const int lhi  = lane >> 4;

  // XCD-aware bijective swizzle: grid 1024 = 8 XCD * 128; 2 XCDs share one nblk (1.9MB W)
  int wg = blockIdx.x;
  int id = (wg & 7) * 128 + (wg >> 3);
  const int mblk = id & 255;
  const int nblk = id >> 8;
  const int row0 = mblk * BM;
  const int col0 = nblk * BN;

  // B DMA: 5 chunks/thread; monotone /20 map (R13-verbatim)
  uint32_t boff[5];
#pragma unroll
  for (int rr = 0; rr < 5; ++rr) {
    int cl = rr * 512 + tid;                  // [0, 2560)
    int o  = cl / 20;
    int sl = cl - o * 20;
    boff[rr] = (uint32_t)(col0 + o) * (uint32_t)KTOT + (uint32_t)sl * 8u;
  }
  const uint32_t dma_l = (uint32_t)tid * 16u;

  // A-gen: isl constant per thread; 2 rows (arow0, arow0+64) per thread
  const int isl = tid & 7;
  const int arow0 = tid >> 3;                 // 0..63
  const uint32_t fw = ((uint32_t)arow0 & 7u) << 4;   // (row&7) invariant under +64

  // fragment read bases (A XOR applied to full address; R9-verbatim)
  const uint32_t fA = (uint32_t)(l16 & 7) << 4;      // row&7 = l16&7
  const uint32_t rA = (uint32_t)(wr * 64 + l16) * A_STRIDE_B + (uint32_t)lhi * 16u;
  const uint32_t rB = (uint32_t)(wc * 32 + l16) * B_STRIDE_B + (uint32_t)lhi * 16u;

  f32x4 acc[4][2] = {};

  // ---- prologue: stage(0) into parity 0, prefetch x(1)
  float xv0, xv1;
  {
    const float* xcol = z + isl;              // s=0 -> i=isl<128 -> z
    float x0 = xcol[(size_t)(row0 + arow0) * 128];
    float x1 = xcol[(size_t)(row0 + arow0 + 64) * 128];
#pragma unroll
    for (int rr = 0; rr < 5; ++rr)
      GLOAD_LDS16(Wb + boff[rr], ldsbuf + 81920u + dma_l + rr * 8192u);
#pragma unroll
    for (int r = 0; r < 2; ++r) {
      float x = (r == 0) ? x0 : x1;
      int arow = arow0 + r * 64;
      float xt = fast_tanh(x);
      float tt = (xt + 1.0f) * 8.0f;
      int   m  = (int)tt; m = m > 16 ? 16 : m;
      float u  = tt - (float)m;
      float omu = 1.0f - u;
      float u2 = u * u, u3 = u2 * u;
      float w0 = omu * omu * omu * (1.0f / 6.0f);
      float w1 = (3.0f * u3 - 6.0f * u2 + 4.0f) * (1.0f / 6.0f);
      float w2 = (-3.0f * u3 + 3.0f * u2 + 3.0f * u + 1.0f) * (1.0f / 6.0f);
      float w3 = u3 * (1.0f / 6.0f);
      float sil = xt / (1.0f + __expf(-xt));
      uint32_t base = (uint32_t)arow * A_STRIDE_B + (uint32_t)isl * 40u;
#pragma unroll
      for (int zz = 0; zz < 5; ++zz)
        *(uint64_t*)(ldsbuf + ((base + zz * 8) ^ fw)) = 0ull;
      *(short*)(ldsbuf + (base ^ fw)) = (short)f2bf(sil);
      *(short*)(ldsbuf + ((base + 2u * (m + 1)) ^ fw)) = (short)f2bf(w0);
      *(short*)(ldsbuf + ((base + 2u * (m + 2)) ^ fw)) = (short)f2bf(w1);
      *(short*)(ldsbuf + ((base + 2u * (m + 3)) ^ fw)) = (short)f2bf(w2);
      if (m < 16)
        *(short*)(ldsbuf + ((base + 2u * (m + 4)) ^ fw)) = (short)f2bf(w3);
    }
    // prefetch x(1)
    const float* xc1 = z + (8 + isl);         // i = 8+isl < 128 -> z
    xv0 = xc1[(size_t)(row0 + arow0) * 128];
    xv1 = xc1[(size_t)(row0 + arow0 + 64) * 128];
  }
  __syncthreads();

  for (int s = 0; s < NSTEP; ++s) {
    const uint32_t pc = (uint32_t)(s & 1);
    const uint32_t pn = pc ^ 1u;
    char* An = ldsbuf + pn * (uint32_t)A_BYTES;
    char* Bn = ldsbuf + 81920u + pn * (uint32_t)B_BYTES;
    const char* Ac = ldsbuf + pc * (uint32_t)A_BYTES;
    const char* Bc = ldsbuf + 81920u + pc * (uint32_t)B_BYTES;

    float xn0 = 0.f, xn1 = 0.f;
    if (s + 1 < NSTEP) {
      // ---- stage B(s+1): DMA into Bn (other parity; compute below reads Bc)
      const uint32_t soff = (uint32_t)(s + 1) * BK;
#pragma unroll
      for (int rr = 0; rr < 5; ++rr)
        GLOAD_LDS16(Wb + boff[rr] + soff, Bn + dma_l + rr * 8192u);
      // ---- stage A(s+1): 2 tasks/thread into An, using xv = x(s+1)
#pragma unroll
      for (int r = 0; r < 2; ++r) {
        float x = (r == 0) ? xv0 : xv1;
        int arow = arow0 + r * 64;
        float xt = fast_tanh(x);
        float tt = (xt + 1.0f) * 8.0f;
        int   m  = (int)tt; m = m > 16 ? 16 : m;
        float u  = tt - (float)m;
        float omu = 1.0f - u;
        float u2 = u * u, u3 = u2 * u;
        float w0 = omu * omu * omu * (1.0f / 6.0f);
        float w1 = (3.0f * u3 - 6.0f * u2 + 4.0f) * (1.0f / 6.0f);
        float w2 = (-3.0f * u3 + 3.0f * u2 + 3.0f * u + 1.0f) * (1.0f / 6.0f);
        float w3 = u3 * (1.0f / 6.0f);
        float sil = xt / (1.0f + __expf(-xt));
        uint32_t base = (uint32_t)arow * A_STRIDE_B + (uint32_t)isl * 40u;
#pragma unroll
        for (int zz = 0; zz < 5; ++zz)
          *(uint64_t*)(An + ((base + zz * 8) ^ fw)) = 0ull;
        *(short*)(An + (base ^ fw)) = (short)f2bf(sil);
        *(short*)(An + ((base + 2u * (m + 1)) ^ fw)) = (short)f2bf(w0);
        *(short*)(An + ((base + 2u * (m + 2)) ^ fw)) = (short)f2bf(w1);
        *(short*)(An + ((base + 2u * (m + 3)) ^ fw)) = (short)f2bf(w2);
        if (m < 16)
          *(short*)(An + ((base + 2u * (m + 4)) ^ fw)) = (short)f2bf(w3);
      }
      // ---- prefetch x(s+2)
      if (s + 2 < NSTEP) {
        int i = (s + 2) * 8 + isl;
        const float* src = (i < 128) ? z : (i < 256 ? ms : md);
        const float* xcol = src + (i & 127);
        xn0 = xcol[(size_t)(row0 + arow0) * 128];
        xn1 = xcol[(size_t)(row0 + arow0 + 64) * 128];
      }
    }

    // ---- compute(s) from current-parity buffers; 5 K-sub-steps; wave tile 64x32
#pragma unroll
    for (int ks = 0; ks < 5; ++ks) {
      bf16x8 af[4], bfr[2];
#pragma unroll
      for (int mi = 0; mi < 4; ++mi)
        af[mi] = *(const bf16x8*)(Ac + ((rA + (uint32_t)(mi * 16) * A_STRIDE_B + ks * 64u) ^ fA));
#pragma unroll
      for (int ni = 0; ni < 2; ++ni)
        bfr[ni] = *(const bf16x8*)(Bc + rB + (uint32_t)(ni * 16) * B_STRIDE_B + ks * 64u);
#pragma unroll
      for (int mi = 0; mi < 4; ++mi)
#pragma unroll
        for (int ni = 0; ni < 2; ++ni)
          acc[mi][ni] = __builtin_amdgcn_mfma_f32_16x16x32_bf16(af[mi], bfr[ni], acc[mi][ni], 0, 0, 0);
    }

    __syncthreads();   // one barrier: drains DMA+A writes (s+1) and orders reads (s)
    xv0 = xn0; xv1 = xn1;
  }

  // ---- epilogue: tanh -> bf16 h
#pragma unroll
  for (int mi = 0; mi < 4; ++mi)
#pragma unroll
    for (int ni = 0; ni < 2; ++ni)
#pragma unroll
      for (int rg = 0; rg < 4; ++rg) {
        int grow = row0 + wr * 64 + mi * 16 + lhi * 4 + rg;
        int gcol = col0 + wc * 32 + ni * 16 + l16;
        hout[(size_t)grow * HID + gcol] = f2bf(fast_tanh(acc[mi][ni][rg]));
      }
}

// ---------------- kfinal (MFMA): 64 rows/block, all 64 output cols ----------------
__global__ __launch_bounds__(256) void kfinal(const unsigned short* __restrict__ h,
                                              const float* __restrict__ lw,
                                              const float* __restrict__ lb,
                                              float* __restrict__ out) {
  __shared__ unsigned short Ws[64 * 512];
  char* WsB = (char*)Ws;
  const int tid  = threadIdx.x;
  const int lane = tid & 63;
  const int wv   = tid >> 6;
  const int l16  = lane & 15;
  const int lhi  = lane >> 4;
  const int row0 = blockIdx.x * 64;

#pragma unroll
  for (int it = 0; it < 16; ++it) {
    int c = it * 256 + tid;
    int r = c >> 6;
    int k8 = (c & 63) * 8;
    const float* g = lw + r * 512 + k8;
    float4 f0 = *(const float4*)g;
    float4 f1 = *(const float4*)(g + 4);
    union { unsigned short s[8]; bf16x8 v; } u;
    u.s[0] = f2bf(f0.x); u.s[1] = f2bf(f0.y); u.s[2] = f2bf(f0.z); u.s[3] = f2bf(f0.w);
    u.s[4] = f2bf(f1.x); u.s[5] = f2bf(f1.y); u.s[6] = f2bf(f1.z); u.s[7] = f2bf(f1.w);
    *(bf16x8*)(WsB + swzw((uint32_t)r * 1024u + (uint32_t)k8 * 2u)) = u.v;
  }
  __syncthreads();

  const int arow = row0 + wv * 16 + l16;
  const unsigned short* ag = h + (size_t)arow * HID + lhi * 8;
  f32x4 acc[4] = {};
#pragma unroll
  for (int ks = 0; ks < 16; ++ks) {
    bf16x8 af = *(const bf16x8*)(ag + ks * 32);
#pragma unroll
    for (int ni = 0; ni < 4; ++ni) {
      uint32_t L = (uint32_t)(ni * 16 + l16) * 1024u + (uint32_t)(ks * 64 + lhi * 16);
      bf16x8 bfr = *(const bf16x8*)(WsB + swzw(L));
      acc[ni] = __builtin_amdgcn_mfma_f32_16x16x32_bf16(af, bfr, acc[ni], 0, 0, 0);
    }
  }
#pragma unroll
  for (int ni = 0; ni < 4; ++ni) {
    int col = ni * 16 + l16;
    float bias = lb[col];
#pragma unroll
    for (int rg = 0; rg < 4; ++rg) {
      int grow = row0 + wv * 16 + lhi * 4 + rg;
      out[(size_t)grow * 64 + col] = acc[ni][rg] + bias;
    }
  }
}

extern "C" void kernel_launch(void* const* d_in, const int* in_sizes, int n_in,
                              void* d_out, int out_size, void* d_ws, size_t ws_size,
                              hipStream_t stream) {
  const float* z  = (const float*)d_in[0];
  const float* ms = (const float*)d_in[1];
  const float* md = (const float*)d_in[2];
  const float* bw = (const float*)d_in[3];
  const float* sw = (const float*)d_in[4];
  const float* lw = (const float*)d_in[5];
  const float* lb = (const float*)d_in[6];
  float* out = (float*)d_out;

  unsigned short* Wb = (unsigned short*)d_ws;                        // 7.5 MiB bf16 W [512][7680]
  unsigned short* hb = (unsigned short*)((char*)d_ws + (8u << 20));  // 32 MiB bf16 h [32768][512]

  (void)hipFuncSetAttribute((const void*)kgemm1,
                            hipFuncAttributeMaxDynamicSharedMemorySize, LDS_BYTES);

  kpack<<<(HID * IN_DIM) / 256, 256, 0, stream>>>(bw, sw, Wb);
  kgemm1<<<1024, 512, LDS_BYTES, stream>>>(z, ms, md, Wb, hb);
  kfinal<<<32768 / 64, 256, 0, stream>>>(hb, lw, lb, out);
}

// Round 18
// 309.524 us; speedup vs baseline: 1.3534x; 1.3534x over previous
//
#include <hip/hip_runtime.h>
#include <hip/hip_bf16.h>
#include <cstdint>

#define DI __device__ __forceinline__

using bf16x8 = __attribute__((ext_vector_type(8))) short;
using f32x4  = __attribute__((ext_vector_type(4))) float;

constexpr int IN_DIM = 384;
constexpr int HID    = 512;
constexpr int KTOT   = IN_DIM * 20;          // 7680: k = i*20 + t
constexpr int BM = 128, BN = 256, BK = 160;  // 8 input dims per K-step
constexpr int NSTEP = KTOT / BK;             // 48
// A: double-buffered LDS, stride 320 + bijective XOR (addr^(row&7)<<4) on write & read
//    (R9/R17-verbatim formulas). ONE barrier per step (write parity != read parity).
// B: NOT in LDS. kpack emits W in MFMA-fragment-linear order; kgemm1 loads each 16x32
//    B-fragment as one coalesced 1KB global read (L2-resident 3.9MB slice per XCD).
//    Plain loads -- no global_load_lds on the B path at all.
constexpr int A_STRIDE_B = 320;
constexpr int A_BYTES    = BM * A_STRIDE_B;        // 40960
constexpr int LDS_BYTES  = 2 * A_BYTES;            // 81920 -> up to 2 blocks/CU

DI unsigned short f2bf(float f) {
  union { float f; uint32_t u; } v; v.f = f;
  uint32_t r = (v.u + 0x7FFFu + ((v.u >> 16) & 1u)) >> 16;
  return (unsigned short)r;
}
DI float fast_tanh(float x) {
  float e = __expf(2.0f * x);
  return 1.0f - 2.0f / (e + 1.0f);
}
DI uint32_t swzw(uint32_t L) { return L ^ ((L >> 6) & 0x70u); }

// ---------------- kpack: W -> bf16 fragment-linear Wf ----------------
// Element (o, k): fragment g = o>>4, q = k>>5; lane = (o&15) + ((k>>3)&3)*16;
// elem offset = (q*32 + g)*512 + lane*8 + (k&7).  k = i*20 + c; c==0 -> base, else spline.
__global__ __launch_bounds__(256) void kpack(const float* __restrict__ bw,
                                             const float* __restrict__ sw,
                                             unsigned short* __restrict__ Wf) {
  int idx = blockIdx.x * 256 + threadIdx.x;   // o*384 + i
  int o = idx / IN_DIM;
  int i = idx - o * IN_DIM;
  const float* sp = sw + (size_t)idx * 19;
  const uint32_t gq  = (uint32_t)(o >> 4);
  const uint32_t l16o = (uint32_t)(o & 15);
#pragma unroll
  for (int c = 0; c < 20; ++c) {
    int k = i * 20 + c;
    uint32_t q  = (uint32_t)k >> 5;
    uint32_t kr = (uint32_t)k & 31u;
    uint32_t lane = l16o + ((kr >> 3) << 4);
    uint32_t off = (q * 32u + gq) * 512u + lane * 8u + (kr & 7u);
    float v = (c == 0) ? bw[idx] : sp[c - 1];
    Wf[off] = f2bf(v);
  }
}

// ---------------- fused KAN GEMM: h = tanh(A(x) @ W^T), 8 waves, wave tile 64x64 ----------------
__global__ __launch_bounds__(512, 2) void kgemm1(const float* __restrict__ z,
                                                 const float* __restrict__ ms,
                                                 const float* __restrict__ md,
                                                 const unsigned short* __restrict__ Wf,
                                                 unsigned short* __restrict__ hout) {
  extern __shared__ char ldsbuf[];            // [A0 @0][A1 @40960]

  const int tid  = threadIdx.x;
  const int lane = tid & 63;
  const int wv   = tid >> 6;                  // 0..7
  const int wr   = wv >> 2;                   // 0..1 : M strip (64 rows)
  const int wc   = wv & 3;                    // 0..3 : N strip (64 cols)
  const int l16  = lane & 15;
  const int lhi  = lane >> 4;

  // XCD-aware bijective swizzle: grid 512 = 8 XCD * 64; XCDs 0-3 -> nblk 0, 4-7 -> nblk 1
  int wg = blockIdx.x;
  int id = (wg & 7) * 64 + (wg >> 3);
  const int mblk = id & 255;
  const int nblk = id >> 8;
  const int row0 = mblk * BM;
  const int col0 = nblk * BN;

  // B global fragment base: g = nblk*16 + wc*4 + ni
  const unsigned short* bpt = Wf + (size_t)(nblk * 16 + wc * 4) * 512 + (size_t)lane * 8;

  // A-gen: isl constant per thread; 2 rows (arow0, arow0+64) per thread
  const int isl = tid & 7;
  const int arow0 = tid >> 3;                 // 0..63
  const uint32_t fw = ((uint32_t)arow0 & 7u) << 4;   // (row&7) invariant under +64

  // A fragment read base (XOR applied to full address; R17-verbatim)
  const uint32_t fA = (uint32_t)(l16 & 7) << 4;      // row&7 = l16&7
  const uint32_t rA = (uint32_t)(wr * 64 + l16) * A_STRIDE_B + (uint32_t)lhi * 16u;

  f32x4 acc[4][4] = {};

  // ---- prologue: stage A(0) into parity 0; prefetch x(1)
  float xv0, xv1;
  {
    const float* xcol = z + isl;              // s=0 -> i=isl<128 -> z
    float x0 = xcol[(size_t)(row0 + arow0) * 128];
    float x1 = xcol[(size_t)(row0 + arow0 + 64) * 128];
#pragma unroll
    for (int r = 0; r < 2; ++r) {
      float x = (r == 0) ? x0 : x1;
      int arow = arow0 + r * 64;
      float xt = fast_tanh(x);
      float tt = (xt + 1.0f) * 8.0f;
      int   m  = (int)tt; m = m > 16 ? 16 : m;
      float u  = tt - (float)m;
      float omu = 1.0f - u;
      float u2 = u * u, u3 = u2 * u;
      float w0 = omu * omu * omu * (1.0f / 6.0f);
      float w1 = (3.0f * u3 - 6.0f * u2 + 4.0f) * (1.0f / 6.0f);
      float w2 = (-3.0f * u3 + 3.0f * u2 + 3.0f * u + 1.0f) * (1.0f / 6.0f);
      float w3 = u3 * (1.0f / 6.0f);
      float sil = xt / (1.0f + __expf(-xt));
      uint32_t base = (uint32_t)arow * A_STRIDE_B + (uint32_t)isl * 40u;
#pragma unroll
      for (int zz = 0; zz < 5; ++zz)
        *(uint64_t*)(ldsbuf + ((base + zz * 8) ^ fw)) = 0ull;
      *(short*)(ldsbuf + (base ^ fw)) = (short)f2bf(sil);
      *(short*)(ldsbuf + ((base + 2u * (m + 1)) ^ fw)) = (short)f2bf(w0);
      *(short*)(ldsbuf + ((base + 2u * (m + 2)) ^ fw)) = (short)f2bf(w1);
      *(short*)(ldsbuf + ((base + 2u * (m + 3)) ^ fw)) = (short)f2bf(w2);
      if (m < 16)
        *(short*)(ldsbuf + ((base + 2u * (m + 4)) ^ fw)) = (short)f2bf(w3);
    }
    const float* xc1 = z + (8 + isl);         // i = 8+isl < 128 -> z
    xv0 = xc1[(size_t)(row0 + arow0) * 128];
    xv1 = xc1[(size_t)(row0 + arow0 + 64) * 128];
  }
  __syncthreads();

  for (int s = 0; s < NSTEP; ++s) {
    const uint32_t pc = (uint32_t)(s & 1);
    const uint32_t pn = pc ^ 1u;
    char* An = ldsbuf + pn * (uint32_t)A_BYTES;
    const char* Ac = ldsbuf + pc * (uint32_t)A_BYTES;

    float xn0 = 0.f, xn1 = 0.f;
    if (s + 1 < NSTEP) {
      // ---- stage A(s+1) into An using xv = x(s+1)
#pragma unroll
      for (int r = 0; r < 2; ++r) {
        float x = (r == 0) ? xv0 : xv1;
        int arow = arow0 + r * 64;
        float xt = fast_tanh(x);
        float tt = (xt + 1.0f) * 8.0f;
        int   m  = (int)tt; m = m > 16 ? 16 : m;
        float u  = tt - (float)m;
        float omu = 1.0f - u;
        float u2 = u * u, u3 = u2 * u;
        float w0 = omu * omu * omu * (1.0f / 6.0f);
        float w1 = (3.0f * u3 - 6.0f * u2 + 4.0f) * (1.0f / 6.0f);
        float w2 = (-3.0f * u3 + 3.0f * u2 + 3.0f * u + 1.0f) * (1.0f / 6.0f);
        float w3 = u3 * (1.0f / 6.0f);
        float sil = xt / (1.0f + __expf(-xt));
        uint32_t base = (uint32_t)arow * A_STRIDE_B + (uint32_t)isl * 40u;
#pragma unroll
        for (int zz = 0; zz < 5; ++zz)
          *(uint64_t*)(An + ((base + zz * 8) ^ fw)) = 0ull;
        *(short*)(An + (base ^ fw)) = (short)f2bf(sil);
        *(short*)(An + ((base + 2u * (m + 1)) ^ fw)) = (short)f2bf(w0);
        *(short*)(An + ((base + 2u * (m + 2)) ^ fw)) = (short)f2bf(w1);
        *(short*)(An + ((base + 2u * (m + 3)) ^ fw)) = (short)f2bf(w2);
        if (m < 16)
          *(short*)(An + ((base + 2u * (m + 4)) ^ fw)) = (short)f2bf(w3);
      }
      // ---- prefetch x(s+2)
      if (s + 2 < NSTEP) {
        int i = (s + 2) * 8 + isl;
        const float* src = (i < 128) ? z : (i < 256 ? ms : md);
        const float* xcol = src + (i & 127);
        xn0 = xcol[(size_t)(row0 + arow0) * 128];
        xn1 = xcol[(size_t)(row0 + arow0 + 64) * 128];
      }
    }

    // ---- compute(s): A frags from LDS (parity pc), B frags as coalesced 1KB global loads
    const size_t qoff = (size_t)s * 5u * 16384u;   // q = s*5 + ks; frag stride 16384 elems
#pragma unroll
    for (int ks = 0; ks < 5; ++ks) {
      bf16x8 af[4], bfr[4];
#pragma unroll
      for (int ni = 0; ni < 4; ++ni)
        bfr[ni] = *(const bf16x8*)(bpt + qoff + (size_t)ks * 16384u + (size_t)ni * 512u);
#pragma unroll
      for (int mi = 0; mi < 4; ++mi)
        af[mi] = *(const bf16x8*)(Ac + ((rA + (uint32_t)(mi * 16) * A_STRIDE_B + ks * 64u) ^ fA));
#pragma unroll
      for (int mi = 0; mi < 4; ++mi)
#pragma unroll
        for (int ni = 0; ni < 4; ++ni)
          acc[mi][ni] = __builtin_amdgcn_mfma_f32_16x16x32_bf16(af[mi], bfr[ni], acc[mi][ni], 0, 0, 0);
    }

    __syncthreads();   // one barrier: A(s+1) writes visible; Ac safe to overwrite next step
    xv0 = xn0; xv1 = xn1;
  }

  // ---- epilogue: tanh -> bf16 h
#pragma unroll
  for (int mi = 0; mi < 4; ++mi)
#pragma unroll
    for (int ni = 0; ni < 4; ++ni)
#pragma unroll
      for (int rg = 0; rg < 4; ++rg) {
        int grow = row0 + wr * 64 + mi * 16 + lhi * 4 + rg;
        int gcol = col0 + wc * 64 + ni * 16 + l16;
        hout[(size_t)grow * HID + gcol] = f2bf(fast_tanh(acc[mi][ni][rg]));
      }
}

// ---------------- kfinal (MFMA): 64 rows/block, all 64 output cols ----------------
__global__ __launch_bounds__(256) void kfinal(const unsigned short* __restrict__ h,
                                              const float* __restrict__ lw,
                                              const float* __restrict__ lb,
                                              float* __restrict__ out) {
  __shared__ unsigned short Ws[64 * 512];
  char* WsB = (char*)Ws;
  const int tid  = threadIdx.x;
  const int lane = tid & 63;
  const int wv   = tid >> 6;
  const int l16  = lane & 15;
  const int lhi  = lane >> 4;
  const int row0 = blockIdx.x * 64;

#pragma unroll
  for (int it = 0; it < 16; ++it) {
    int c = it * 256 + tid;
    int r = c >> 6;
    int k8 = (c & 63) * 8;
    const float* g = lw + r * 512 + k8;
    float4 f0 = *(const float4*)g;
    float4 f1 = *(const float4*)(g + 4);
    union { unsigned short s[8]; bf16x8 v; } u;
    u.s[0] = f2bf(f0.x); u.s[1] = f2bf(f0.y); u.s[2] = f2bf(f0.z); u.s[3] = f2bf(f0.w);
    u.s[4] = f2bf(f1.x); u.s[5] = f2bf(f1.y); u.s[6] = f2bf(f1.z); u.s[7] = f2bf(f1.w);
    *(bf16x8*)(WsB + swzw((uint32_t)r * 1024u + (uint32_t)k8 * 2u)) = u.v;
  }
  __syncthreads();

  const int arow = row0 + wv * 16 + l16;
  const unsigned short* ag = h + (size_t)arow * HID + lhi * 8;
  f32x4 acc[4] = {};
#pragma unroll
  for (int ks = 0; ks < 16; ++ks) {
    bf16x8 af = *(const bf16x8*)(ag + ks * 32);
#pragma unroll
    for (int ni = 0; ni < 4; ++ni) {
      uint32_t L = (uint32_t)(ni * 16 + l16) * 1024u + (uint32_t)(ks * 64 + lhi * 16);
      bf16x8 bfr = *(const bf16x8*)(WsB + swzw(L));
      acc[ni] = __builtin_amdgcn_mfma_f32_16x16x32_bf16(af, bfr, acc[ni], 0, 0, 0);
    }
  }
#pragma unroll
  for (int ni = 0; ni < 4; ++ni) {
    int col = ni * 16 + l16;
    float bias = lb[col];
#pragma unroll
    for (int rg = 0; rg < 4; ++rg) {
      int grow = row0 + wv * 16 + lhi * 4 + rg;
      out[(size_t)grow * 64 + col] = acc[ni][rg] + bias;
    }
  }
}

extern "C" void kernel_launch(void* const* d_in, const int* in_sizes, int n_in,
                              void* d_out, int out_size, void* d_ws, size_t ws_size,
                              hipStream_t stream) {
  const float* z  = (const float*)d_in[0];
  const float* ms = (const float*)d_in[1];
  const float* md = (const float*)d_in[2];
  const float* bw = (const float*)d_in[3];
  const float* sw = (const float*)d_in[4];
  const float* lw = (const float*)d_in[5];
  const float* lb = (const float*)d_in[6];
  float* out = (float*)d_out;

  unsigned short* Wf = (unsigned short*)d_ws;                        // 7.9 MiB fragment-linear W
  unsigned short* hb = (unsigned short*)((char*)d_ws + (8u << 20));  // 32 MiB bf16 h [32768][512]

  (void)hipFuncSetAttribute((const void*)kgemm1,
                            hipFuncAttributeMaxDynamicSharedMemorySize, LDS_BYTES);

  kpack<<<(HID * IN_DIM) / 256, 256, 0, stream>>>(bw, sw, Wf);
  kgemm1<<<512, 512, LDS_BYTES, stream>>>(z, ms, md, Wf, hb);
  kfinal<<<32768 / 64, 256, 0, stream>>>(hb, lw, lb, out);
}